// Round 1
// baseline (1930.244 us; speedup 1.0000x reference)
//
#include <hip/hip_runtime.h>

#define NSRC 100000
#define NTGT 50000
#define NE   600000
#define CH   128
#define NREL 7
#define NTYP 4

// workspace layout (bytes)
static constexpr size_t CNT_OFF    = 0;                                   // int[NTGT*NREL]
static constexpr size_t TCNT_OFF   = (size_t)NTGT * NREL * 4;             // int[NTYP]
static constexpr size_t BUCKET_OFF = TCNT_OFF + 64;                       // int[NTYP*NTGT]
static constexpr size_t AGG_OFF    = BUCKET_OFF + (size_t)NTYP * NTGT * 4 + 128; // float[NTGT*CH]

// XOR-swizzled LDS layout: row-major 128 floats/row, float4 chunk kc permuted by
// (row>>2)&7 so the 16 distinct col-rows (or 4 row-rows) a wave reads per k-step
// spread across all 32 banks. 64KB total -> fits the static LDS limit exactly.
__device__ __forceinline__ int lidx(int row, int kc) {
  return row * CH + ((kc ^ ((row >> 2) & 7)) << 2);
}

__global__ void k_count(const int* __restrict__ edst, const int* __restrict__ etyp,
                        int* __restrict__ cnt) {
  int i = blockIdx.x * 256 + threadIdx.x;
  if (i < NE) atomicAdd(&cnt[edst[i] * NREL + etyp[i]], 1);
}

__global__ void k_bucket(const int* __restrict__ ntyp, int* __restrict__ tcnt,
                         int* __restrict__ bucket) {
  int v = blockIdx.x * 256 + threadIdx.x;
  if (v < NTGT) {
    int t = ntyp[v];
    int slot = atomicAdd(&tcnt[t], 1);
    bucket[t * NTGT + slot] = v;
  }
}

// 32 threads per edge, 4 channels each; fp32 HW atomics into agg[dst].
__global__ void k_scatter(const float* __restrict__ xsrc, const int* __restrict__ esrc,
                          const int* __restrict__ edst, const int* __restrict__ etyp,
                          float* __restrict__ agg, int rel) {
  int gid = blockIdx.x * 256 + threadIdx.x;
  int c4 = (gid & 31) * 4;
  int slot = gid >> 5;
  int nslots = (gridDim.x * 256) >> 5;
  for (int e = slot; e < NE; e += nslots) {
    if (etyp[e] != rel) continue;
    int s = esrc[e], d = edst[e];
    float4 x = *(const float4*)(xsrc + (size_t)s * CH + c4);
    float* a = agg + (size_t)d * CH + c4;
    unsafeAtomicAdd(a + 0, x.x);
    unsafeAtomicAdd(a + 1, x.y);
    unsafeAtomicAdd(a + 2, x.z);
    unsafeAtomicAdd(a + 3, x.w);
  }
}

// out[v][o] += (agg[v]/max(cnt[v,rel],1)) . W_rel[o]   64x64 tile, 4x4 per thread
__global__ __launch_bounds__(256) void k_relgemm(
    const float* __restrict__ agg, const float* __restrict__ relw,
    const int* __restrict__ cnt, float* __restrict__ out, int rel) {
  __shared__ float aS[64 * CH];
  __shared__ float wS[64 * CH];
  int row0 = blockIdx.x * 64;
  int col0 = blockIdx.y * 64;
  const float* W = relw + (size_t)rel * CH * CH;

  for (int idx = threadIdx.x; idx < 64 * 32; idx += 256) {
    int c = idx >> 5, kc = idx & 31;
    float4 w4 = *(const float4*)(W + (size_t)(col0 + c) * CH + kc * 4);
    *(float4*)&wS[lidx(c, kc)] = w4;
  }
  for (int idx = threadIdx.x; idx < 64 * 32; idx += 256) {
    int rv = idx >> 5, kc = idx & 31;
    int v = row0 + rv;
    float4 a4 = make_float4(0.f, 0.f, 0.f, 0.f);
    if (v < NTGT) {
      a4 = *(const float4*)(agg + (size_t)v * CH + kc * 4);
      int c = cnt[v * NREL + rel];
      float inv = 1.0f / (float)(c > 1 ? c : 1);
      a4.x *= inv; a4.y *= inv; a4.z *= inv; a4.w *= inv;
    }
    *(float4*)&aS[lidx(rv, kc)] = a4;
  }
  __syncthreads();

  int tr = threadIdx.x >> 4, tc = threadIdx.x & 15;
  int v0 = tr * 4, o0 = tc * 4;
  float acc[4][4] = {};
  for (int kc = 0; kc < 32; ++kc) {
    float4 a[4], w[4];
#pragma unroll
    for (int i = 0; i < 4; ++i) a[i] = *(const float4*)&aS[lidx(v0 + i, kc)];
#pragma unroll
    for (int j = 0; j < 4; ++j) w[j] = *(const float4*)&wS[lidx(o0 + j, kc)];
#pragma unroll
    for (int i = 0; i < 4; ++i)
#pragma unroll
      for (int j = 0; j < 4; ++j)
        acc[i][j] += a[i].x * w[j].x + a[i].y * w[j].y + a[i].z * w[j].z + a[i].w * w[j].w;
  }
#pragma unroll
  for (int i = 0; i < 4; ++i) {
    int v = row0 + v0 + i;
    if (v < NTGT) {
      float4* p = (float4*)(out + (size_t)v * CH + col0 + o0);
      float4 o4 = *p;
      o4.x += acc[i][0]; o4.y += acc[i][1]; o4.z += acc[i][2]; o4.w += acc[i][3];
      *p = o4;
    }
  }
}

// out[v] = x_target[v] @ root_w[t]^T + root_b[t], rows gathered from type bucket.
__global__ __launch_bounds__(256) void k_rootgemm(
    const float* __restrict__ xt, const float* __restrict__ rootw,
    const float* __restrict__ rootb, const int* __restrict__ bucket,
    const int* __restrict__ tcnt, float* __restrict__ out, int typ) {
  __shared__ float aS[64 * CH];
  __shared__ float wS[64 * CH];
  int nb = tcnt[typ];
  int row0 = blockIdx.x * 64;
  if (row0 >= nb) return;
  int col0 = blockIdx.y * 64;
  const float* W = rootw + (size_t)typ * CH * CH;
  const int* bk = bucket + (size_t)typ * NTGT;

  for (int idx = threadIdx.x; idx < 64 * 32; idx += 256) {
    int c = idx >> 5, kc = idx & 31;
    float4 w4 = *(const float4*)(W + (size_t)(col0 + c) * CH + kc * 4);
    *(float4*)&wS[lidx(c, kc)] = w4;
  }
  for (int idx = threadIdx.x; idx < 64 * 32; idx += 256) {
    int rv = idx >> 5, kc = idx & 31;
    int rr = row0 + rv;
    float4 a4 = make_float4(0.f, 0.f, 0.f, 0.f);
    if (rr < nb) {
      int v = bk[rr];
      a4 = *(const float4*)(xt + (size_t)v * CH + kc * 4);
    }
    *(float4*)&aS[lidx(rv, kc)] = a4;
  }
  __syncthreads();

  int tr = threadIdx.x >> 4, tc = threadIdx.x & 15;
  int v0 = tr * 4, o0 = tc * 4;
  float acc[4][4] = {};
  for (int kc = 0; kc < 32; ++kc) {
    float4 a[4], w[4];
#pragma unroll
    for (int i = 0; i < 4; ++i) a[i] = *(const float4*)&aS[lidx(v0 + i, kc)];
#pragma unroll
    for (int j = 0; j < 4; ++j) w[j] = *(const float4*)&wS[lidx(o0 + j, kc)];
#pragma unroll
    for (int i = 0; i < 4; ++i)
#pragma unroll
      for (int j = 0; j < 4; ++j)
        acc[i][j] += a[i].x * w[j].x + a[i].y * w[j].y + a[i].z * w[j].z + a[i].w * w[j].w;
  }
  float4 b4 = *(const float4*)(rootb + (size_t)typ * CH + col0 + o0);
#pragma unroll
  for (int i = 0; i < 4; ++i) {
    int rr = row0 + v0 + i;
    if (rr < nb) {
      int v = bk[rr];
      float4 o4;
      o4.x = acc[i][0] + b4.x;
      o4.y = acc[i][1] + b4.y;
      o4.z = acc[i][2] + b4.z;
      o4.w = acc[i][3] + b4.w;
      *(float4*)(out + (size_t)v * CH + col0 + o0) = o4;
    }
  }
}

extern "C" void kernel_launch(void* const* d_in, const int* in_sizes, int n_in,
                              void* d_out, int out_size, void* d_ws, size_t ws_size,
                              hipStream_t stream) {
  (void)in_sizes; (void)n_in; (void)out_size; (void)ws_size;
  const float* xsrc  = (const float*)d_in[0];
  const float* xt    = (const float*)d_in[1];
  const float* relw  = (const float*)d_in[2];
  const float* rootw = (const float*)d_in[3];
  const float* rootb = (const float*)d_in[4];
  const int* esrc = (const int*)d_in[5];
  const int* edst = (const int*)d_in[6];
  const int* etyp = (const int*)d_in[7];
  const int* ntyp = (const int*)d_in[8];
  float* out = (float*)d_out;

  char* ws = (char*)d_ws;
  int* cnt    = (int*)(ws + CNT_OFF);
  int* tcnt   = (int*)(ws + TCNT_OFF);
  int* bucket = (int*)(ws + BUCKET_OFF);
  float* agg  = (float*)(ws + AGG_OFF);

  // zero cnt + tcnt + bucket region (d_ws is re-poisoned to 0xAA before each call)
  hipMemsetAsync(ws, 0, AGG_OFF, stream);
  k_count<<<dim3((NE + 255) / 256), dim3(256), 0, stream>>>(edst, etyp, cnt);
  k_bucket<<<dim3((NTGT + 255) / 256), dim3(256), 0, stream>>>(ntyp, tcnt, bucket);

  dim3 g((NTGT + 63) / 64, 2);
  for (int t = 0; t < NTYP; ++t)
    k_rootgemm<<<g, dim3(256), 0, stream>>>(xt, rootw, rootb, bucket, tcnt, out, t);

  for (int r = 0; r < NREL; ++r) {
    hipMemsetAsync(agg, 0, (size_t)NTGT * CH * sizeof(float), stream);
    k_scatter<<<dim3(8192), dim3(256), 0, stream>>>(xsrc, esrc, edst, etyp, agg, r);
    k_relgemm<<<g, dim3(256), 0, stream>>>(agg, relw, cnt, out, r);
  }
}

// Round 2
// 1713.085 us; speedup vs baseline: 1.1268x; 1.1268x over previous
//
#include <hip/hip_runtime.h>

#define NSRC 100000
#define NTGT 50000
#define NE   600000
#define CH   128
#define NREL 7
#define NTYP 4

// ---- workspace layout (bytes) ----
static constexpr size_t CNT_OFF    = 0;                          // int[NTGT*NREL]  1.4MB
static constexpr size_t TCNT_OFF   = 1400064;                    // int[NTYP]
static constexpr size_t ECNT_OFF   = 1400128;                    // int[NREL]
static constexpr size_t EOFF_OFF   = 1400192;                    // int[NREL+1]
static constexpr size_t ECUR_OFF   = 1400256;                    // int[NREL]
static constexpr size_t BUCKET_OFF = 1400320;                    // int[NTYP*NTGT] 0.8MB
static constexpr size_t ZERO_END   = BUCKET_OFF + (size_t)NTYP * NTGT * 4;  // memset [0, ZERO_END)
static constexpr size_t EIDX_OFF   = ((ZERO_END + 63) / 64) * 64;           // int[NE] 2.4MB
static constexpr size_t AGG_OFF    = ((EIDX_OFF + (size_t)NE * 4 + 63) / 64) * 64; // float[NTGT*CH] 25.6MB

// XOR-swizzled LDS layout (conflict-free b128 column reads), 64KB total.
__device__ __forceinline__ int lidx(int row, int kc) {
  return row * CH + ((kc ^ ((row >> 2) & 7)) << 2);
}

__global__ void k_count(const int* __restrict__ edst, const int* __restrict__ etyp,
                        int* __restrict__ cnt) {
  int i = blockIdx.x * 256 + threadIdx.x;
  if (i < NE) atomicAdd(&cnt[edst[i] * NREL + etyp[i]], 1);
}

// node bucketing: LDS histogram + one global reservation per (block, type)
__global__ void k_bucket(const int* __restrict__ ntyp, int* __restrict__ tcnt,
                         int* __restrict__ bucket) {
  __shared__ int lcnt[NTYP];
  __shared__ int lbase[NTYP];
  int v = blockIdx.x * 256 + threadIdx.x;
  if (threadIdx.x < NTYP) lcnt[threadIdx.x] = 0;
  __syncthreads();
  int t = 0, r = 0;
  bool ok = v < NTGT;
  if (ok) { t = ntyp[v]; r = atomicAdd(&lcnt[t], 1); }
  __syncthreads();
  if (threadIdx.x < NTYP) lbase[threadIdx.x] = atomicAdd(&tcnt[threadIdx.x], lcnt[threadIdx.x]);
  __syncthreads();
  if (ok) bucket[t * NTGT + lbase[t] + r] = v;
}

// edge histogram by relation
__global__ void k_ecount(const int* __restrict__ etyp, int* __restrict__ ecnt) {
  __shared__ int lcnt[NREL];
  int e = blockIdx.x * 256 + threadIdx.x;
  if (threadIdx.x < NREL) lcnt[threadIdx.x] = 0;
  __syncthreads();
  if (e < NE) atomicAdd(&lcnt[etyp[e]], 1);
  __syncthreads();
  if (threadIdx.x < NREL) atomicAdd(&ecnt[threadIdx.x], lcnt[threadIdx.x]);
}

__global__ void k_escan(const int* __restrict__ ecnt, int* __restrict__ eoff,
                        int* __restrict__ ecur) {
  if (threadIdx.x == 0) {
    int acc = 0;
    for (int r = 0; r < NREL; ++r) { eoff[r] = acc; ecur[r] = acc; acc += ecnt[r]; }
    eoff[NREL] = acc;
  }
}

// edge bucketing into eidx, grouped by relation
__global__ void k_ebucket(const int* __restrict__ etyp, int* __restrict__ ecur,
                          int* __restrict__ eidx) {
  __shared__ int lcnt[NREL];
  __shared__ int lbase[NREL];
  int e = blockIdx.x * 256 + threadIdx.x;
  if (threadIdx.x < NREL) lcnt[threadIdx.x] = 0;
  __syncthreads();
  int t = 0, r = 0;
  bool ok = e < NE;
  if (ok) { t = etyp[e]; r = atomicAdd(&lcnt[t], 1); }
  __syncthreads();
  if (threadIdx.x < NREL) lbase[threadIdx.x] = atomicAdd(&ecur[threadIdx.x], lcnt[threadIdx.x]);
  __syncthreads();
  if (ok) eidx[lbase[t] + r] = e;
}

// 32 lanes per edge, float4 per lane; fp32 HW atomics into agg[dst].
__global__ void k_scatter(const float* __restrict__ xsrc, const int* __restrict__ esrc,
                          const int* __restrict__ edst, const int* __restrict__ eidx,
                          const int* __restrict__ eoff, float* __restrict__ agg, int rel) {
  int lo = eoff[rel], hi = eoff[rel + 1];
  int gid = blockIdx.x * 256 + threadIdx.x;
  int c4 = (gid & 31) * 4;
  int slot = gid >> 5;
  int nslots = (gridDim.x * 256) >> 5;
  for (int i = lo + slot; i < hi; i += nslots) {
    int e = eidx[i];
    int s = esrc[e], d = edst[e];
    float4 x = *(const float4*)(xsrc + (size_t)s * CH + c4);
    float* a = agg + (size_t)d * CH + c4;
    unsafeAtomicAdd(a + 0, x.x);
    unsafeAtomicAdd(a + 1, x.y);
    unsafeAtomicAdd(a + 2, x.z);
    unsafeAtomicAdd(a + 3, x.w);
  }
}

// out[v][o] += (agg[v]/max(cnt[v,rel],1)) . W_rel[o]   64x64 tile, 4x4 per thread
__global__ __launch_bounds__(256) void k_relgemm(
    const float* __restrict__ agg, const float* __restrict__ relw,
    const int* __restrict__ cnt, float* __restrict__ out, int rel) {
  __shared__ float aS[64 * CH];
  __shared__ float wS[64 * CH];
  int row0 = blockIdx.x * 64;
  int col0 = blockIdx.y * 64;
  const float* W = relw + (size_t)rel * CH * CH;

  for (int idx = threadIdx.x; idx < 64 * 32; idx += 256) {
    int c = idx >> 5, kc = idx & 31;
    float4 w4 = *(const float4*)(W + (size_t)(col0 + c) * CH + kc * 4);
    *(float4*)&wS[lidx(c, kc)] = w4;
  }
  for (int idx = threadIdx.x; idx < 64 * 32; idx += 256) {
    int rv = idx >> 5, kc = idx & 31;
    int v = row0 + rv;
    float4 a4 = make_float4(0.f, 0.f, 0.f, 0.f);
    if (v < NTGT) {
      a4 = *(const float4*)(agg + (size_t)v * CH + kc * 4);
      int c = cnt[v * NREL + rel];
      float inv = 1.0f / (float)(c > 1 ? c : 1);
      a4.x *= inv; a4.y *= inv; a4.z *= inv; a4.w *= inv;
    }
    *(float4*)&aS[lidx(rv, kc)] = a4;
  }
  __syncthreads();

  int tr = threadIdx.x >> 4, tc = threadIdx.x & 15;
  int v0 = tr * 4, o0 = tc * 4;
  float acc[4][4] = {};
  for (int kc = 0; kc < 32; ++kc) {
    float4 a[4], w[4];
#pragma unroll
    for (int i = 0; i < 4; ++i) a[i] = *(const float4*)&aS[lidx(v0 + i, kc)];
#pragma unroll
    for (int j = 0; j < 4; ++j) w[j] = *(const float4*)&wS[lidx(o0 + j, kc)];
#pragma unroll
    for (int i = 0; i < 4; ++i)
#pragma unroll
      for (int j = 0; j < 4; ++j)
        acc[i][j] += a[i].x * w[j].x + a[i].y * w[j].y + a[i].z * w[j].z + a[i].w * w[j].w;
  }
#pragma unroll
  for (int i = 0; i < 4; ++i) {
    int v = row0 + v0 + i;
    if (v < NTGT) {
      float4* p = (float4*)(out + (size_t)v * CH + col0 + o0);
      float4 o4 = *p;
      o4.x += acc[i][0]; o4.y += acc[i][1]; o4.z += acc[i][2]; o4.w += acc[i][3];
      *p = o4;
    }
  }
}

// out[v] = x_target[v] @ root_w[t]^T + root_b[t], rows gathered from type bucket.
__global__ __launch_bounds__(256) void k_rootgemm(
    const float* __restrict__ xt, const float* __restrict__ rootw,
    const float* __restrict__ rootb, const int* __restrict__ bucket,
    const int* __restrict__ tcnt, float* __restrict__ out, int typ) {
  __shared__ float aS[64 * CH];
  __shared__ float wS[64 * CH];
  int nb = tcnt[typ];
  int row0 = blockIdx.x * 64;
  if (row0 >= nb) return;
  int col0 = blockIdx.y * 64;
  const float* W = rootw + (size_t)typ * CH * CH;
  const int* bk = bucket + (size_t)typ * NTGT;

  for (int idx = threadIdx.x; idx < 64 * 32; idx += 256) {
    int c = idx >> 5, kc = idx & 31;
    float4 w4 = *(const float4*)(W + (size_t)(col0 + c) * CH + kc * 4);
    *(float4*)&wS[lidx(c, kc)] = w4;
  }
  for (int idx = threadIdx.x; idx < 64 * 32; idx += 256) {
    int rv = idx >> 5, kc = idx & 31;
    int rr = row0 + rv;
    float4 a4 = make_float4(0.f, 0.f, 0.f, 0.f);
    if (rr < nb) {
      int v = bk[rr];
      a4 = *(const float4*)(xt + (size_t)v * CH + kc * 4);
    }
    *(float4*)&aS[lidx(rv, kc)] = a4;
  }
  __syncthreads();

  int tr = threadIdx.x >> 4, tc = threadIdx.x & 15;
  int v0 = tr * 4, o0 = tc * 4;
  float acc[4][4] = {};
  for (int kc = 0; kc < 32; ++kc) {
    float4 a[4], w[4];
#pragma unroll
    for (int i = 0; i < 4; ++i) a[i] = *(const float4*)&aS[lidx(v0 + i, kc)];
#pragma unroll
    for (int j = 0; j < 4; ++j) w[j] = *(const float4*)&wS[lidx(o0 + j, kc)];
#pragma unroll
    for (int i = 0; i < 4; ++i)
#pragma unroll
      for (int j = 0; j < 4; ++j)
        acc[i][j] += a[i].x * w[j].x + a[i].y * w[j].y + a[i].z * w[j].z + a[i].w * w[j].w;
  }
  float4 b4 = *(const float4*)(rootb + (size_t)typ * CH + col0 + o0);
#pragma unroll
  for (int i = 0; i < 4; ++i) {
    int rr = row0 + v0 + i;
    if (rr < nb) {
      int v = bk[rr];
      float4 o4;
      o4.x = acc[i][0] + b4.x;
      o4.y = acc[i][1] + b4.y;
      o4.z = acc[i][2] + b4.z;
      o4.w = acc[i][3] + b4.w;
      *(float4*)(out + (size_t)v * CH + col0 + o0) = o4;
    }
  }
}

extern "C" void kernel_launch(void* const* d_in, const int* in_sizes, int n_in,
                              void* d_out, int out_size, void* d_ws, size_t ws_size,
                              hipStream_t stream) {
  (void)in_sizes; (void)n_in; (void)out_size; (void)ws_size;
  const float* xsrc  = (const float*)d_in[0];
  const float* xt    = (const float*)d_in[1];
  const float* relw  = (const float*)d_in[2];
  const float* rootw = (const float*)d_in[3];
  const float* rootb = (const float*)d_in[4];
  const int* esrc = (const int*)d_in[5];
  const int* edst = (const int*)d_in[6];
  const int* etyp = (const int*)d_in[7];
  const int* ntyp = (const int*)d_in[8];
  float* out = (float*)d_out;

  char* ws = (char*)d_ws;
  int* cnt    = (int*)(ws + CNT_OFF);
  int* tcnt   = (int*)(ws + TCNT_OFF);
  int* ecnt   = (int*)(ws + ECNT_OFF);
  int* eoff   = (int*)(ws + EOFF_OFF);
  int* ecur   = (int*)(ws + ECUR_OFF);
  int* bucket = (int*)(ws + BUCKET_OFF);
  int* eidx   = (int*)(ws + EIDX_OFF);
  float* agg  = (float*)(ws + AGG_OFF);

  hipMemsetAsync(ws, 0, ZERO_END, stream);

  k_count<<<dim3((NE + 255) / 256), dim3(256), 0, stream>>>(edst, etyp, cnt);
  k_bucket<<<dim3((NTGT + 255) / 256), dim3(256), 0, stream>>>(ntyp, tcnt, bucket);
  k_ecount<<<dim3((NE + 255) / 256), dim3(256), 0, stream>>>(etyp, ecnt);
  k_escan<<<dim3(1), dim3(64), 0, stream>>>(ecnt, eoff, ecur);
  k_ebucket<<<dim3((NE + 255) / 256), dim3(256), 0, stream>>>(etyp, ecur, eidx);

  dim3 g((NTGT + 63) / 64, 2);
  for (int t = 0; t < NTYP; ++t)
    k_rootgemm<<<g, dim3(256), 0, stream>>>(xt, rootw, rootb, bucket, tcnt, out, t);

  for (int r = 0; r < NREL; ++r) {
    hipMemsetAsync(agg, 0, (size_t)NTGT * CH * sizeof(float), stream);
    k_scatter<<<dim3(4096), dim3(256), 0, stream>>>(xsrc, esrc, edst, eidx, eoff, agg, r);
    k_relgemm<<<g, dim3(256), 0, stream>>>(agg, relw, cnt, out, r);
  }
}

// Round 3
// 599.054 us; speedup vs baseline: 3.2222x; 2.8596x over previous
//
#include <hip/hip_runtime.h>

#define NSRC 100000
#define NTGT 50000
#define NE   600000
#define CH   128
#define NREL 7
#define NTYP 4
#define NP   (NREL * NTGT)          // 350000 (rel,dst) pairs
#define NB   ((NP + 1023) / 1024)   // scan blocks (342)
#define MAXBLK ((NTGT + 63) / 64)   // 782

typedef __attribute__((ext_vector_type(4))) float f32x4;
typedef __attribute__((ext_vector_type(8))) short bf16x8;
typedef unsigned int uint;
typedef unsigned short ushort;

// ---- workspace layout ----
static constexpr size_t A256(size_t x) { return (x + 255) & ~(size_t)255; }
static constexpr size_t CNT_O   = 0;                                   // int[NP]
static constexpr size_t TCNT_O  = A256(CNT_O + (size_t)NP * 4);        // int[NTYP]
static constexpr size_t ZERO_END= TCNT_O + 256;                        // memset range
static constexpr size_t BSE_O   = ZERO_END;                            // int[NB]
static constexpr size_t BSR_O   = A256(BSE_O + (size_t)NB * 4);
static constexpr size_t BBE_O   = A256(BSR_O + (size_t)NB * 4);
static constexpr size_t BBR_O   = A256(BBE_O + (size_t)NB * 4);
static constexpr size_t CUR_O   = A256(BBR_O + (size_t)NB * 4);        // int[NP]
static constexpr size_t PLO_O   = A256(CUR_O + (size_t)NP * 4);        // int[NP]
static constexpr size_t PN_O    = A256(PLO_O + (size_t)NP * 4);        // int[NP]
static constexpr size_t PINV_O  = A256(PN_O + (size_t)NP * 4);         // float[NP]
static constexpr size_t PDST_O  = A256(PINV_O + (size_t)NP * 4);       // int[NP]
static constexpr size_t RELO_O  = A256(PDST_O + (size_t)NP * 4);       // int[NREL+1]
static constexpr size_t BKT_O   = A256(RELO_O + 64);                   // int[NTYP*NTGT]
static constexpr size_t SEDGE_O = A256(BKT_O + (size_t)NTYP * NTGT * 4); // int[NE]
static constexpr size_t WB_O    = A256(SEDGE_O + (size_t)NE * 4);      // bf16[(NREL+NTYP)*CH*CH]

__device__ __forceinline__ uint bfpack(float a, float b) {
  uint ua = __float_as_uint(a); ua = (ua + 0x7fff + ((ua >> 16) & 1)) >> 16;
  uint ub = __float_as_uint(b); ub = (ub + 0x7fff + ((ub >> 16) & 1)) >> 16;
  return ua | (ub << 16);
}

__global__ void k_count(const int* __restrict__ edst, const int* __restrict__ etyp,
                        int* __restrict__ cnt) {
  int i = blockIdx.x * 256 + threadIdx.x;
  if (i < NE) atomicAdd(&cnt[etyp[i] * NTGT + edst[i]], 1);
}

__global__ void k_bucket(const int* __restrict__ ntyp, int* __restrict__ tcnt,
                         int* __restrict__ bucket) {
  __shared__ int lcnt[NTYP];
  __shared__ int lbase[NTYP];
  int v = blockIdx.x * 256 + threadIdx.x;
  if (threadIdx.x < NTYP) lcnt[threadIdx.x] = 0;
  __syncthreads();
  int t = 0, r = 0;
  bool ok = v < NTGT;
  if (ok) { t = ntyp[v]; r = atomicAdd(&lcnt[t], 1); }
  __syncthreads();
  if (threadIdx.x < NTYP) lbase[threadIdx.x] = atomicAdd(&tcnt[threadIdx.x], lcnt[threadIdx.x]);
  __syncthreads();
  if (ok) bucket[t * NTGT + lbase[t] + r] = v;
}

// scan stage 1: per-1024-entry block sums of (edge count, nonzero-pair count)
__global__ __launch_bounds__(256) void k_s1(const int* __restrict__ cnt,
                                            int* __restrict__ bsE, int* __restrict__ bsR) {
  __shared__ int sE[256], sR[256];
  int t = threadIdx.x, p0 = blockIdx.x * 1024 + t * 4;
  int e = 0, r = 0;
#pragma unroll
  for (int j = 0; j < 4; ++j) {
    int p = p0 + j;
    if (p < NP) { int c = cnt[p]; e += c; r += (c > 0); }
  }
  sE[t] = e; sR[t] = r; __syncthreads();
  for (int s = 128; s > 0; s >>= 1) {
    if (t < s) { sE[t] += sE[t + s]; sR[t] += sR[t + s]; }
    __syncthreads();
  }
  if (t == 0) { bsE[blockIdx.x] = sE[0]; bsR[blockIdx.x] = sR[0]; }
}

// scan stage 2: exclusive scan of block sums (NB<=512), writes total rows to reloff[NREL]
__global__ __launch_bounds__(512) void k_s2(const int* __restrict__ bsE, const int* __restrict__ bsR,
                                            int* __restrict__ bbE, int* __restrict__ bbR,
                                            int* __restrict__ reloff) {
  __shared__ int sE[512], sR[512];
  int t = threadIdx.x;
  int e = (t < NB) ? bsE[t] : 0;
  int r = (t < NB) ? bsR[t] : 0;
  sE[t] = e; sR[t] = r; __syncthreads();
  for (int s = 1; s < 512; s <<= 1) {
    int ae = 0, ar = 0;
    if (t >= s) { ae = sE[t - s]; ar = sR[t - s]; }
    __syncthreads();
    sE[t] += ae; sR[t] += ar;
    __syncthreads();
  }
  if (t < NB) { bbE[t] = sE[t] - e; bbR[t] = sR[t] - r; }
  if (t == NB - 1) reloff[NREL] = sR[t];
}

// scan stage 3: final offsets; emit compact pair arrays + per-rel row offsets + cur
__global__ __launch_bounds__(256) void k_s3(const int* __restrict__ cnt,
    const int* __restrict__ bbE, const int* __restrict__ bbR,
    int* __restrict__ cur, int* __restrict__ plo, int* __restrict__ pn,
    float* __restrict__ pinv, int* __restrict__ pdst, int* __restrict__ reloff) {
  __shared__ int sE[256], sR[256];
  int t = threadIdx.x, p0 = blockIdx.x * 1024 + t * 4;
  int c[4]; int e = 0, r = 0;
#pragma unroll
  for (int j = 0; j < 4; ++j) {
    int p = p0 + j;
    c[j] = (p < NP) ? cnt[p] : 0;
    e += c[j]; r += (c[j] > 0);
  }
  sE[t] = e; sR[t] = r; __syncthreads();
  for (int s = 1; s < 256; s <<= 1) {
    int ae = 0, ar = 0;
    if (t >= s) { ae = sE[t - s]; ar = sR[t - s]; }
    __syncthreads();
    sE[t] += ae; sR[t] += ar;
    __syncthreads();
  }
  int baseE = bbE[blockIdx.x] + sE[t] - e;
  int baseR = bbR[blockIdx.x] + sR[t] - r;
#pragma unroll
  for (int j = 0; j < 4; ++j) {
    int p = p0 + j;
    if (p < NP) {
      cur[p] = baseE;
      if ((p % NTGT) == 0) reloff[p / NTGT] = baseR;
      if (c[j] > 0) {
        plo[baseR] = baseE; pn[baseR] = c[j];
        pinv[baseR] = 1.0f / (float)c[j];
        pdst[baseR] = p % NTGT;
        baseR++;
      }
      baseE += c[j];
    }
  }
}

__global__ void k_esort(const int* __restrict__ esrc, const int* __restrict__ edst,
                        const int* __restrict__ etyp, int* __restrict__ cur,
                        int* __restrict__ sedge) {
  int i = blockIdx.x * 256 + threadIdx.x;
  if (i < NE) {
    int p = etyp[i] * NTGT + edst[i];
    int pos = atomicAdd(&cur[p], 1);
    sedge[pos] = esrc[i];
  }
}

__global__ void k_wconv(const float* __restrict__ relw, const float* __restrict__ rootw,
                        ushort* __restrict__ wb) {
  int i = blockIdx.x * 256 + threadIdx.x;
  const int nrel = NREL * CH * CH;
  if (i < (NREL + NTYP) * CH * CH) {
    float v = (i < nrel) ? relw[i] : rootw[i - nrel];
    uint u = __float_as_uint(v);
    wb[i] = (ushort)((u + 0x7fff + ((u >> 16) & 1)) >> 16);
  }
}

// ---- fused gather+mean+bf16 MFMA GEMM for one relation ----
// block: 256 thr = 4 waves; 64 compact rows x 128 cols, K=128.
// wave w owns rows [w*16, w*16+16). LDS strip 16x128 bf16, 16B-chunk XOR swizzle.
__global__ __launch_bounds__(256) void k_rel(const float* __restrict__ xsrc,
    const ushort* __restrict__ wb, const int* __restrict__ plo, const int* __restrict__ pn,
    const float* __restrict__ pinv, const int* __restrict__ pdst,
    const int* __restrict__ reloff, const int* __restrict__ sedge,
    float* __restrict__ out, int rel) {
  __shared__ ushort As[4 * 16 * CH];
  int base = reloff[rel], relend = reloff[rel + 1];
  int row0 = blockIdx.x * 64;
  if (row0 >= relend - base) return;
  int wv = threadIdx.x >> 6, ln = threadIdx.x & 63;
  ushort* strip = As + wv * (16 * CH);

  // build: gather + mean 16 rows, fp32 accum, pack bf16x2 into swizzled LDS
  for (int i = 0; i < 16; ++i) {
    int gr = base + row0 + wv * 16 + i;
    float ax = 0.f, ay = 0.f, inv = 0.f;
    if (gr < relend) {
      int lo = plo[gr], n = pn[gr];
      inv = pinv[gr];
      for (int q = 0; q < n; ++q) {
        int s = sedge[lo + q];
        const float* xp = xsrc + (size_t)s * CH + (ln << 1);
        ax += xp[0]; ay += xp[1];
      }
    }
    uint w = bfpack(ax * inv, ay * inv);
    int c = ln >> 2;                                   // 16B chunk 0..15
    *(uint*)&strip[((i * 16 + (c ^ i)) << 3) + ((ln & 3) << 1)] = w;
  }
  // wave-local LDS use: no barrier needed, compiler inserts lgkmcnt waits
  int m = ln & 15, quad = ln >> 4;
  bf16x8 aF[4];
#pragma unroll
  for (int ks = 0; ks < 4; ++ks) {
    int c = ks * 4 + quad;
    aF[ks] = *(const bf16x8*)&strip[(m * 16 + (c ^ m)) << 3];
  }
  const ushort* W = wb + (size_t)rel * CH * CH;
  f32x4 acc[8];
#pragma unroll
  for (int ct = 0; ct < 8; ++ct) acc[ct] = (f32x4){0.f, 0.f, 0.f, 0.f};
#pragma unroll
  for (int ct = 0; ct < 8; ++ct) {
    int n = ct * 16 + m;
#pragma unroll
    for (int ks = 0; ks < 4; ++ks) {
      bf16x8 bF = *(const bf16x8*)(W + (size_t)n * CH + ks * 32 + quad * 8);
      acc[ct] = __builtin_amdgcn_mfma_f32_16x16x32_bf16(aF[ks], bF, acc[ct], 0, 0, 0);
    }
  }
  // epilogue: C/D layout col=lane&15, rowm=quad*4+reg
  int drow[4];
#pragma unroll
  for (int reg = 0; reg < 4; ++reg) {
    int gro = base + row0 + wv * 16 + quad * 4 + reg;
    drow[reg] = (gro < relend) ? pdst[gro] : -1;
  }
#pragma unroll
  for (int ct = 0; ct < 8; ++ct)
#pragma unroll
    for (int reg = 0; reg < 4; ++reg)
      if (drow[reg] >= 0) out[(size_t)drow[reg] * CH + ct * 16 + m] += acc[ct][reg];
}

// ---- root linear, all 4 node types in one launch (types partition rows) ----
__global__ __launch_bounds__(256) void k_root(const float* __restrict__ xt,
    const ushort* __restrict__ wb, const float* __restrict__ rootb,
    const int* __restrict__ bucket, const int* __restrict__ tcnt,
    float* __restrict__ out) {
  __shared__ ushort As[4 * 16 * CH];
  int typ = blockIdx.x / MAXBLK, blk = blockIdx.x % MAXBLK;
  int nb = tcnt[typ];
  int row0 = blk * 64;
  if (row0 >= nb) return;
  const int* bk = bucket + (size_t)typ * NTGT;
  int wv = threadIdx.x >> 6, ln = threadIdx.x & 63;
  ushort* strip = As + wv * (16 * CH);

  for (int i = 0; i < 16; ++i) {
    int rr = row0 + wv * 16 + i;
    float ax = 0.f, ay = 0.f;
    if (rr < nb) {
      int v = bk[rr];
      const float* xp = xt + (size_t)v * CH + (ln << 1);
      ax = xp[0]; ay = xp[1];
    }
    uint w = bfpack(ax, ay);
    int c = ln >> 2;
    *(uint*)&strip[((i * 16 + (c ^ i)) << 3) + ((ln & 3) << 1)] = w;
  }
  int m = ln & 15, quad = ln >> 4;
  bf16x8 aF[4];
#pragma unroll
  for (int ks = 0; ks < 4; ++ks) {
    int c = ks * 4 + quad;
    aF[ks] = *(const bf16x8*)&strip[(m * 16 + (c ^ m)) << 3];
  }
  const ushort* W = wb + (size_t)(NREL + typ) * CH * CH;
  f32x4 acc[8];
#pragma unroll
  for (int ct = 0; ct < 8; ++ct) acc[ct] = (f32x4){0.f, 0.f, 0.f, 0.f};
#pragma unroll
  for (int ct = 0; ct < 8; ++ct) {
    int n = ct * 16 + m;
#pragma unroll
    for (int ks = 0; ks < 4; ++ks) {
      bf16x8 bF = *(const bf16x8*)(W + (size_t)n * CH + ks * 32 + quad * 8);
      acc[ct] = __builtin_amdgcn_mfma_f32_16x16x32_bf16(aF[ks], bF, acc[ct], 0, 0, 0);
    }
  }
  int vrow[4];
#pragma unroll
  for (int reg = 0; reg < 4; ++reg) {
    int rro = row0 + wv * 16 + quad * 4 + reg;
    vrow[reg] = (rro < nb) ? bk[rro] : -1;
  }
#pragma unroll
  for (int ct = 0; ct < 8; ++ct) {
    float b = rootb[typ * CH + ct * 16 + m];
#pragma unroll
    for (int reg = 0; reg < 4; ++reg)
      if (vrow[reg] >= 0) out[(size_t)vrow[reg] * CH + ct * 16 + m] = acc[ct][reg] + b;
  }
}

extern "C" void kernel_launch(void* const* d_in, const int* in_sizes, int n_in,
                              void* d_out, int out_size, void* d_ws, size_t ws_size,
                              hipStream_t stream) {
  (void)in_sizes; (void)n_in; (void)out_size; (void)ws_size;
  const float* xsrc  = (const float*)d_in[0];
  const float* xt    = (const float*)d_in[1];
  const float* relw  = (const float*)d_in[2];
  const float* rootw = (const float*)d_in[3];
  const float* rootb = (const float*)d_in[4];
  const int* esrc = (const int*)d_in[5];
  const int* edst = (const int*)d_in[6];
  const int* etyp = (const int*)d_in[7];
  const int* ntyp = (const int*)d_in[8];
  float* out = (float*)d_out;

  char* ws = (char*)d_ws;
  int*   cnt    = (int*)(ws + CNT_O);
  int*   tcnt   = (int*)(ws + TCNT_O);
  int*   bsE    = (int*)(ws + BSE_O);
  int*   bsR    = (int*)(ws + BSR_O);
  int*   bbE    = (int*)(ws + BBE_O);
  int*   bbR    = (int*)(ws + BBR_O);
  int*   cur    = (int*)(ws + CUR_O);
  int*   plo    = (int*)(ws + PLO_O);
  int*   pn     = (int*)(ws + PN_O);
  float* pinv   = (float*)(ws + PINV_O);
  int*   pdst   = (int*)(ws + PDST_O);
  int*   reloff = (int*)(ws + RELO_O);
  int*   bucket = (int*)(ws + BKT_O);
  int*   sedge  = (int*)(ws + SEDGE_O);
  ushort* wb    = (ushort*)(ws + WB_O);

  hipMemsetAsync(ws, 0, ZERO_END, stream);
  k_count<<<dim3((NE + 255) / 256), dim3(256), 0, stream>>>(edst, etyp, cnt);
  k_bucket<<<dim3((NTGT + 255) / 256), dim3(256), 0, stream>>>(ntyp, tcnt, bucket);
  k_s1<<<dim3(NB), dim3(256), 0, stream>>>(cnt, bsE, bsR);
  k_s2<<<dim3(1), dim3(512), 0, stream>>>(bsE, bsR, bbE, bbR, reloff);
  k_s3<<<dim3(NB), dim3(256), 0, stream>>>(cnt, bbE, bbR, cur, plo, pn, pinv, pdst, reloff);
  k_esort<<<dim3((NE + 255) / 256), dim3(256), 0, stream>>>(esrc, edst, etyp, cur, sedge);
  k_wconv<<<dim3(((NREL + NTYP) * CH * CH + 255) / 256), dim3(256), 0, stream>>>(relw, rootw, wb);

  k_root<<<dim3(NTYP * MAXBLK), dim3(256), 0, stream>>>(xt, wb, rootb, bucket, tcnt, out);
  for (int r = 0; r < NREL; ++r)
    k_rel<<<dim3(MAXBLK), dim3(256), 0, stream>>>(xsrc, wb, plo, pn, pinv, pdst, reloff,
                                                  sedge, out, r);
}

// Round 4
// 411.910 us; speedup vs baseline: 4.6861x; 1.4543x over previous
//
#include <hip/hip_runtime.h>

#define NSRC 100000
#define NTGT 50000
#define NE   600000
#define CH   128
#define NREL 7
#define NTYP 4
#define NP   (NREL * NTGT)          // 350000 (rel,dst) pairs
#define NB   ((NP + 1023) / 1024)   // scan blocks (342)
#define MAXBLK ((NTGT + 63) / 64)   // 782

typedef __attribute__((ext_vector_type(4))) float f32x4;
typedef __attribute__((ext_vector_type(8))) short bf16x8;
typedef unsigned int uint;
typedef unsigned short ushort;

// ---- workspace layout ----
static constexpr size_t A256(size_t x) { return (x + 255) & ~(size_t)255; }
static constexpr size_t CNT_O   = 0;                                   // int[NP]
static constexpr size_t TCNT_O  = A256(CNT_O + (size_t)NP * 4);        // int[NTYP]
static constexpr size_t ZERO_END= TCNT_O + 256;                        // memset range
static constexpr size_t BSE_O   = ZERO_END;                            // int[NB]
static constexpr size_t BSR_O   = A256(BSE_O + (size_t)NB * 4);
static constexpr size_t BBE_O   = A256(BSR_O + (size_t)NB * 4);
static constexpr size_t BBR_O   = A256(BBE_O + (size_t)NB * 4);
static constexpr size_t CUR_O   = A256(BBR_O + (size_t)NB * 4);        // int[NP]
static constexpr size_t PLO_O   = A256(CUR_O + (size_t)NP * 4);        // int[NP]
static constexpr size_t PN_O    = A256(PLO_O + (size_t)NP * 4);        // int[NP]
static constexpr size_t PINV_O  = A256(PN_O + (size_t)NP * 4);         // float[NP]
static constexpr size_t PDST_O  = A256(PINV_O + (size_t)NP * 4);       // int[NP]
static constexpr size_t RELO_O  = A256(PDST_O + (size_t)NP * 4);       // int[NREL+1]
static constexpr size_t BKT_O   = A256(RELO_O + 64);                   // int[NTYP*NTGT]
static constexpr size_t SEDGE_O = A256(BKT_O + (size_t)NTYP * NTGT * 4); // int[NE]
static constexpr size_t WB_O    = A256(SEDGE_O + (size_t)NE * 4);      // bf16[11*CH*CH]
static constexpr size_t XB_O    = A256(WB_O + (size_t)(NREL + NTYP) * CH * CH * 2); // bf16[NSRC*CH]
static constexpr size_t XTB_O   = A256(XB_O + (size_t)NSRC * CH * 2);  // bf16[NTGT*CH]

__device__ __forceinline__ uint bfpack(float a, float b) {
  uint ua = __float_as_uint(a); ua = (ua + 0x7fff + ((ua >> 16) & 1)) >> 16;
  uint ub = __float_as_uint(b); ub = (ub + 0x7fff + ((ub >> 16) & 1)) >> 16;
  return ua | (ub << 16);
}
__device__ __forceinline__ ushort f2b(float x) {
  uint u = __float_as_uint(x);
  return (ushort)((u + 0x7fff + ((u >> 16) & 1)) >> 16);
}
__device__ __forceinline__ float bl(uint u) { return __uint_as_float(u << 16); }
__device__ __forceinline__ float bh(uint u) { return __uint_as_float(u & 0xffff0000u); }

__global__ void k_count(const int* __restrict__ edst, const int* __restrict__ etyp,
                        int* __restrict__ cnt) {
  int i = blockIdx.x * 256 + threadIdx.x;
  if (i < NE) atomicAdd(&cnt[etyp[i] * NTGT + edst[i]], 1);
}

__global__ void k_bucket(const int* __restrict__ ntyp, int* __restrict__ tcnt,
                         int* __restrict__ bucket) {
  __shared__ int lcnt[NTYP];
  __shared__ int lbase[NTYP];
  int v = blockIdx.x * 256 + threadIdx.x;
  if (threadIdx.x < NTYP) lcnt[threadIdx.x] = 0;
  __syncthreads();
  int t = 0, r = 0;
  bool ok = v < NTGT;
  if (ok) { t = ntyp[v]; r = atomicAdd(&lcnt[t], 1); }
  __syncthreads();
  if (threadIdx.x < NTYP) lbase[threadIdx.x] = atomicAdd(&tcnt[threadIdx.x], lcnt[threadIdx.x]);
  __syncthreads();
  if (ok) bucket[t * NTGT + lbase[t] + r] = v;
}

__global__ __launch_bounds__(256) void k_s1(const int* __restrict__ cnt,
                                            int* __restrict__ bsE, int* __restrict__ bsR) {
  __shared__ int sE[256], sR[256];
  int t = threadIdx.x, p0 = blockIdx.x * 1024 + t * 4;
  int e = 0, r = 0;
#pragma unroll
  for (int j = 0; j < 4; ++j) {
    int p = p0 + j;
    if (p < NP) { int c = cnt[p]; e += c; r += (c > 0); }
  }
  sE[t] = e; sR[t] = r; __syncthreads();
  for (int s = 128; s > 0; s >>= 1) {
    if (t < s) { sE[t] += sE[t + s]; sR[t] += sR[t + s]; }
    __syncthreads();
  }
  if (t == 0) { bsE[blockIdx.x] = sE[0]; bsR[blockIdx.x] = sR[0]; }
}

__global__ __launch_bounds__(512) void k_s2(const int* __restrict__ bsE, const int* __restrict__ bsR,
                                            int* __restrict__ bbE, int* __restrict__ bbR,
                                            int* __restrict__ reloff) {
  __shared__ int sE[512], sR[512];
  int t = threadIdx.x;
  int e = (t < NB) ? bsE[t] : 0;
  int r = (t < NB) ? bsR[t] : 0;
  sE[t] = e; sR[t] = r; __syncthreads();
  for (int s = 1; s < 512; s <<= 1) {
    int ae = 0, ar = 0;
    if (t >= s) { ae = sE[t - s]; ar = sR[t - s]; }
    __syncthreads();
    sE[t] += ae; sR[t] += ar;
    __syncthreads();
  }
  if (t < NB) { bbE[t] = sE[t] - e; bbR[t] = sR[t] - r; }
  if (t == NB - 1) reloff[NREL] = sR[t];
}

__global__ __launch_bounds__(256) void k_s3(const int* __restrict__ cnt,
    const int* __restrict__ bbE, const int* __restrict__ bbR,
    int* __restrict__ cur, int* __restrict__ plo, int* __restrict__ pn,
    float* __restrict__ pinv, int* __restrict__ pdst, int* __restrict__ reloff) {
  __shared__ int sE[256], sR[256];
  int t = threadIdx.x, p0 = blockIdx.x * 1024 + t * 4;
  int c[4]; int e = 0, r = 0;
#pragma unroll
  for (int j = 0; j < 4; ++j) {
    int p = p0 + j;
    c[j] = (p < NP) ? cnt[p] : 0;
    e += c[j]; r += (c[j] > 0);
  }
  sE[t] = e; sR[t] = r; __syncthreads();
  for (int s = 1; s < 256; s <<= 1) {
    int ae = 0, ar = 0;
    if (t >= s) { ae = sE[t - s]; ar = sR[t - s]; }
    __syncthreads();
    sE[t] += ae; sR[t] += ar;
    __syncthreads();
  }
  int baseE = bbE[blockIdx.x] + sE[t] - e;
  int baseR = bbR[blockIdx.x] + sR[t] - r;
#pragma unroll
  for (int j = 0; j < 4; ++j) {
    int p = p0 + j;
    if (p < NP) {
      cur[p] = baseE;
      if ((p % NTGT) == 0) reloff[p / NTGT] = baseR;
      if (c[j] > 0) {
        plo[baseR] = baseE; pn[baseR] = c[j];
        pinv[baseR] = 1.0f / (float)c[j];
        pdst[baseR] = p % NTGT;
        baseR++;
      }
      baseE += c[j];
    }
  }
}

__global__ void k_esort(const int* __restrict__ esrc, const int* __restrict__ edst,
                        const int* __restrict__ etyp, int* __restrict__ cur,
                        int* __restrict__ sedge) {
  int i = blockIdx.x * 256 + threadIdx.x;
  if (i < NE) {
    int p = etyp[i] * NTGT + edst[i];
    int pos = atomicAdd(&cur[p], 1);
    sedge[pos] = esrc[i];
  }
}

// fp32 -> bf16 conversion for x_src, x_target, and all weights (one pass)
__global__ void k_conv(const float* __restrict__ xsrc, const float* __restrict__ xt,
                       const float* __restrict__ relw, const float* __restrict__ rootw,
                       ushort* __restrict__ xb, ushort* __restrict__ xtb,
                       ushort* __restrict__ wb) {
  const long long NXB = (long long)NSRC * CH / 4;
  const long long NXT = (long long)NTGT * CH / 4;
  const long long NWR = (long long)NREL * CH * CH / 4;
  const long long NWT = (long long)NTYP * CH * CH / 4;
  long long i4 = (long long)blockIdx.x * 256 + threadIdx.x;
  const float* src; ushort* dst; long long off;
  if (i4 < NXB) { src = xsrc; dst = xb; off = i4; }
  else if (i4 < NXB + NXT) { src = xt; dst = xtb; off = i4 - NXB; }
  else if (i4 < NXB + NXT + NWR) { src = relw; dst = wb; off = i4 - NXB - NXT; }
  else if (i4 < NXB + NXT + NWR + NWT) {
    src = rootw; dst = wb + (size_t)NREL * CH * CH; off = i4 - NXB - NXT - NWR;
  } else return;
  float4 v = *(const float4*)(src + off * 4);
  uint lo = (uint)f2b(v.x) | ((uint)f2b(v.y) << 16);
  uint hi = (uint)f2b(v.z) | ((uint)f2b(v.w) << 16);
  uint2 o = make_uint2(lo, hi);
  *(uint2*)(dst + off * 4) = o;
}

// out[v][c] = rootb[ntyp[v]][c]   (bias pre-fill so everything else atomic-adds)
__global__ void k_init(const float* __restrict__ rootb, const int* __restrict__ ntyp,
                       float* __restrict__ out) {
  int idx = blockIdx.x * 256 + threadIdx.x;
  if (idx >= NTGT * 32) return;
  int v = idx >> 5, c4 = (idx & 31) << 2;
  int t = ntyp[v];
  *(float4*)(out + (size_t)v * CH + c4) = *(const float4*)(rootb + (size_t)t * CH + c4);
}

// shared MFMA tail: A from swizzled LDS strip, B from global weights, atomic-add out
__device__ __forceinline__ void mfma_tail(const ushort* strip, const ushort* W,
                                          int m, int quad, const int* rowmap,
                                          float* __restrict__ out) {
  bf16x8 aF[4];
#pragma unroll
  for (int ks = 0; ks < 4; ++ks) {
    int c = ks * 4 + quad;
    aF[ks] = *(const bf16x8*)&strip[(m * 16 + (c ^ m)) << 3];
  }
  f32x4 acc[8];
#pragma unroll
  for (int ct = 0; ct < 8; ++ct) acc[ct] = (f32x4){0.f, 0.f, 0.f, 0.f};
#pragma unroll
  for (int ct = 0; ct < 8; ++ct) {
    int n = ct * 16 + m;
#pragma unroll
    for (int ks = 0; ks < 4; ++ks) {
      bf16x8 bF = *(const bf16x8*)(W + (size_t)n * CH + ks * 32 + quad * 8);
      acc[ct] = __builtin_amdgcn_mfma_f32_16x16x32_bf16(aF[ks], bF, acc[ct], 0, 0, 0);
    }
  }
#pragma unroll
  for (int ct = 0; ct < 8; ++ct)
#pragma unroll
    for (int reg = 0; reg < 4; ++reg)
      if (rowmap[reg] >= 0)
        unsafeAtomicAdd(&out[(size_t)rowmap[reg] * CH + ct * 16 + m], acc[ct][reg]);
}

// single launch: y<NREL -> relation tiles (gather+mean+GEMM), y>=NREL -> root linear
__global__ __launch_bounds__(256) void k_mega(const ushort* __restrict__ xb,
    const ushort* __restrict__ xtb, const ushort* __restrict__ wb,
    const int* __restrict__ plo, const int* __restrict__ pn,
    const float* __restrict__ pinv, const int* __restrict__ pdst,
    const int* __restrict__ reloff, const int* __restrict__ sedge,
    const int* __restrict__ bucket, const int* __restrict__ tcnt,
    float* __restrict__ out) {
  __shared__ ushort As[4 * 16 * CH];
  int wv = threadIdx.x >> 6, ln = threadIdx.x & 63;
  ushort* strip = As + wv * (16 * CH);
  int m = ln & 15, quad = ln >> 4;
  int y = blockIdx.y;

  if (y < NREL) {
    int rel = y;
    int base = reloff[rel], relend = reloff[rel + 1];
    int row0 = blockIdx.x * 64;
    if (row0 >= relend - base) return;
    for (int i = 0; i < 16; ++i) {
      int gr = base + row0 + wv * 16 + i;
      float ax = 0.f, ay = 0.f, inv = 0.f;
      if (gr < relend) {
        int lo = plo[gr], n = pn[gr];
        inv = pinv[gr];
        const int* sp = sedge + lo;
        int q = 0;
        for (; q + 1 < n; q += 2) {
          int s0 = sp[q], s1 = sp[q + 1];
          uint u0 = *(const uint*)(xb + (size_t)s0 * CH + (ln << 1));
          uint u1 = *(const uint*)(xb + (size_t)s1 * CH + (ln << 1));
          ax += bl(u0) + bl(u1);
          ay += bh(u0) + bh(u1);
        }
        if (q < n) {
          uint u0 = *(const uint*)(xb + (size_t)sp[q] * CH + (ln << 1));
          ax += bl(u0); ay += bh(u0);
        }
      }
      uint w = bfpack(ax * inv, ay * inv);
      int c = ln >> 2;
      *(uint*)&strip[((i * 16 + (c ^ i)) << 3) + ((ln & 3) << 1)] = w;
    }
    int rowmap[4];
#pragma unroll
    for (int reg = 0; reg < 4; ++reg) {
      int gro = base + row0 + wv * 16 + quad * 4 + reg;
      rowmap[reg] = (gro < relend) ? pdst[gro] : -1;
    }
    mfma_tail(strip, wb + (size_t)rel * CH * CH, m, quad, rowmap, out);
  } else {
    int typ = y - NREL;
    int nb = tcnt[typ];
    int row0 = blockIdx.x * 64;
    if (row0 >= nb) return;
    const int* bk = bucket + (size_t)typ * NTGT;
    for (int i = 0; i < 16; ++i) {
      int rr = row0 + wv * 16 + i;
      uint w = 0;
      if (rr < nb) {
        int v = bk[rr];
        w = *(const uint*)(xtb + (size_t)v * CH + (ln << 1));
      }
      int c = ln >> 2;
      *(uint*)&strip[((i * 16 + (c ^ i)) << 3) + ((ln & 3) << 1)] = w;
    }
    int rowmap[4];
#pragma unroll
    for (int reg = 0; reg < 4; ++reg) {
      int rro = row0 + wv * 16 + quad * 4 + reg;
      rowmap[reg] = (rro < nb) ? bk[rro] : -1;
    }
    mfma_tail(strip, wb + (size_t)(NREL + typ) * CH * CH, m, quad, rowmap, out);
  }
}

extern "C" void kernel_launch(void* const* d_in, const int* in_sizes, int n_in,
                              void* d_out, int out_size, void* d_ws, size_t ws_size,
                              hipStream_t stream) {
  (void)in_sizes; (void)n_in; (void)out_size; (void)ws_size;
  const float* xsrc  = (const float*)d_in[0];
  const float* xt    = (const float*)d_in[1];
  const float* relw  = (const float*)d_in[2];
  const float* rootw = (const float*)d_in[3];
  const float* rootb = (const float*)d_in[4];
  const int* esrc = (const int*)d_in[5];
  const int* edst = (const int*)d_in[6];
  const int* etyp = (const int*)d_in[7];
  const int* ntyp = (const int*)d_in[8];
  float* out = (float*)d_out;

  char* ws = (char*)d_ws;
  int*   cnt    = (int*)(ws + CNT_O);
  int*   tcnt   = (int*)(ws + TCNT_O);
  int*   bsE    = (int*)(ws + BSE_O);
  int*   bsR    = (int*)(ws + BSR_O);
  int*   bbE    = (int*)(ws + BBE_O);
  int*   bbR    = (int*)(ws + BBR_O);
  int*   cur    = (int*)(ws + CUR_O);
  int*   plo    = (int*)(ws + PLO_O);
  int*   pn     = (int*)(ws + PN_O);
  float* pinv   = (float*)(ws + PINV_O);
  int*   pdst   = (int*)(ws + PDST_O);
  int*   reloff = (int*)(ws + RELO_O);
  int*   bucket = (int*)(ws + BKT_O);
  int*   sedge  = (int*)(ws + SEDGE_O);
  ushort* wb    = (ushort*)(ws + WB_O);
  ushort* xb    = (ushort*)(ws + XB_O);
  ushort* xtb   = (ushort*)(ws + XTB_O);

  hipMemsetAsync(ws, 0, ZERO_END, stream);
  k_count<<<dim3((NE + 255) / 256), dim3(256), 0, stream>>>(edst, etyp, cnt);
  k_bucket<<<dim3((NTGT + 255) / 256), dim3(256), 0, stream>>>(ntyp, tcnt, bucket);
  k_s1<<<dim3(NB), dim3(256), 0, stream>>>(cnt, bsE, bsR);
  k_s2<<<dim3(1), dim3(512), 0, stream>>>(bsE, bsR, bbE, bbR, reloff);
  k_s3<<<dim3(NB), dim3(256), 0, stream>>>(cnt, bbE, bbR, cur, plo, pn, pinv, pdst, reloff);
  k_esort<<<dim3((NE + 255) / 256), dim3(256), 0, stream>>>(esrc, edst, etyp, cur, sedge);
  {
    long long tot4 = (long long)NSRC * CH / 4 + (long long)NTGT * CH / 4 +
                     (long long)(NREL + NTYP) * CH * CH / 4;
    k_conv<<<dim3((unsigned)((tot4 + 255) / 256)), dim3(256), 0, stream>>>(
        xsrc, xt, relw, rootw, xb, xtb, wb);
  }
  k_init<<<dim3((NTGT * 32 + 255) / 256), dim3(256), 0, stream>>>(rootb, ntyp, out);
  k_mega<<<dim3(MAXBLK, NREL + NTYP), dim3(256), 0, stream>>>(
      xb, xtb, wb, plo, pn, pinv, pdst, reloff, sedge, bucket, tcnt, out);
}